// Round 17
// baseline (134.528 us; speedup 1.0000x reference)
//
#include <hip/hip_runtime.h>

#define NROWS 4096
#define DCOLS 8192
#define DIM   256
#define NHALF 4096

typedef __attribute__((ext_vector_type(8))) short bf16x8;
typedef __attribute__((ext_vector_type(4))) float f32x4;
typedef __attribute__((ext_vector_type(4))) unsigned short ushort4v;
typedef __attribute__((ext_vector_type(2))) _Float16 half2v;
typedef __attribute__((ext_vector_type(4))) _Float16 half4v;
typedef __attribute__((ext_vector_type(8))) _Float16 half8;

#define LN128 4.852030263919617f
// mean sampled over 512 x-rows x 4096 pos cols
#define MEAN_DIV (1.0 / 2097152.0)

static __device__ __forceinline__ unsigned short f2bf(float f) {
  union { float f; unsigned int i; } v; v.f = f;
  unsigned int x = v.i;
  return (unsigned short)((x + 0x7fffu + ((x >> 16) & 1u)) >> 16);
}

static __device__ __forceinline__ half2v cvt_pk(float a, float b) {
  return __builtin_bit_cast(half2v, __builtin_amdgcn_cvt_pkrtz(a, b));
}

// 8 fp8 (two dwords) -> half8 via f32
static __device__ __forceinline__ half8 fp8x8_to_h8(int lo, int hi) {
  auto p0 = __builtin_amdgcn_cvt_pk_f32_fp8(lo, false);
  auto p1 = __builtin_amdgcn_cvt_pk_f32_fp8(lo, true);
  auto p2 = __builtin_amdgcn_cvt_pk_f32_fp8(hi, false);
  auto p3 = __builtin_amdgcn_cvt_pk_f32_fp8(hi, true);
  half2v h0 = cvt_pk(p0[0], p0[1]);
  half2v h1 = cvt_pk(p1[0], p1[1]);
  half2v h2 = cvt_pk(p2[0], p2[1]);
  half2v h3 = cvt_pk(p3[0], p3[1]);
  return (half8){h0[0], h0[1], h1[0], h1[1], h2[0], h2[1], h3[0], h3[1]};
}

static __device__ __forceinline__ void gload_lds16(const void* g, void* l) {
  __builtin_amdgcn_global_load_lds(
      (const __attribute__((address_space(1))) void*)g,
      (__attribute__((address_space(3))) void*)l, 16, 0, 0);
}

static __device__ __forceinline__ float hsum8(half8 v) {
  float s = 0.f;
  #pragma unroll
  for (int u = 0; u < 8; ++u) s += (float)v[u];
  return s;
}

#define WREDUCE(v) { v += __shfl_xor(v, 1); v += __shfl_xor(v, 2); v += __shfl_xor(v, 4); \
                     v += __shfl_xor(v, 8); v += __shfl_xor(v, 16); v += __shfl_xor(v, 32); }

// ---------------- prep: bf16 convert + row norms (wave per row, float4) ----------------
__global__ __launch_bounds__(256) void k_prep(
    const float* __restrict__ x, const float* __restrict__ ypos,
    const float* __restrict__ yneg, unsigned short* __restrict__ xb,
    unsigned short* __restrict__ yb, float* __restrict__ xx, float* __restrict__ yy) {
  const int lane = threadIdx.x & 63, w = threadIdx.x >> 6;
  const int b = blockIdx.x * 4 + w;   // 0..12287
  const float* src; unsigned short* dst; float* nrm;
  if (b < 4096)      { src = x + (size_t)b * DIM;             dst = xb + (size_t)b * DIM;            nrm = xx + b; }
  else if (b < 8192) { int r = b - 4096; src = yneg + (size_t)r * DIM; dst = yb + (size_t)r * DIM;   nrm = yy + r; }
  else               { int r = b - 8192; src = ypos + (size_t)r * DIM; dst = yb + (size_t)(NHALF + r) * DIM; nrm = yy + NHALF + r; }
  float4 v = *(const float4*)(src + lane * 4);
  ushort4v ov = { f2bf(v.x), f2bf(v.y), f2bf(v.z), f2bf(v.w) };
  *(ushort4v*)(dst + lane * 4) = ov;
  float s = v.x * v.x + v.y * v.y + v.z * v.z + v.w * v.w;
  WREDUCE(s);
  if (lane == 0) nrm[0] = s;
}

// ---------------- transpose y f32 (8192x256) -> ybt fp16 (256x8192) ----------------
__global__ __launch_bounds__(256) void k_transpose(
    const float* __restrict__ ypos, const float* __restrict__ yneg,
    unsigned short* __restrict__ ybt) {
  __shared__ unsigned short tile[64][68];
  int r0 = blockIdx.x * 64;   // yb-row space: 0-4095 neg, 4096-8191 pos
  int c0 = blockIdx.y * 64;
  const float* src = (r0 < NHALF) ? (yneg + (size_t)r0 * DIM)
                                  : (ypos + (size_t)(r0 - NHALF) * DIM);
  int tx = threadIdx.x & 63, ty = threadIdx.x >> 6;
  #pragma unroll
  for (int it = 0; it < 16; ++it) {
    int r = it * 4 + ty;
    _Float16 h = (_Float16)src[(size_t)r * DIM + c0 + tx];
    tile[r][tx] = __builtin_bit_cast(unsigned short, h);
  }
  __syncthreads();
  #pragma unroll
  for (int it = 0; it < 16; ++it) {
    int c = it * 4 + ty;
    ybt[(size_t)(c0 + c) * DCOLS + r0 + tx] = tile[tx][c];
  }
}

// ---------------- mean GEMM: sampled (512 x-rows) x pos half, no stores ----------------
__global__ __launch_bounds__(256) void k_mean(
    const unsigned short* __restrict__ xb, const unsigned short* __restrict__ yb,
    const float* __restrict__ xx, const float* __restrict__ yy,
    double* __restrict__ meanacc) {
  __shared__ unsigned short As[128 * 64];
  __shared__ unsigned short Bs[128 * 64];
  __shared__ float red[4];
  const int bj = NHALF + blockIdx.x * 128;   // pos half
  const int bi = blockIdx.y * 128;           // rows 0..511
  const int tid = threadIdx.x;
  const int lane = tid & 63, wid = tid >> 6;
  const int wr = wid >> 1, wc = wid & 1;
  f32x4 acc[4][4];
  #pragma unroll
  for (int m = 0; m < 4; ++m)
    #pragma unroll
    for (int n = 0; n < 4; ++n) acc[m][n] = (f32x4){0.f, 0.f, 0.f, 0.f};

  for (int k0 = 0; k0 < DIM; k0 += 64) {
    __syncthreads();
    #pragma unroll
    for (int it = 0; it < 4; ++it) {
      int L = it * 256 + tid;
      int row = L >> 3;
      int cb = (L & 7) * 16;
      int cbs = cb ^ ((row & 7) << 4);
      gload_lds16(xb + (size_t)(bi + row) * DIM + k0 + (cbs >> 1), (char*)As + L * 16);
      gload_lds16(yb + (size_t)(bj + row) * DIM + k0 + (cbs >> 1), (char*)Bs + L * 16);
    }
    __syncthreads();
    #pragma unroll
    for (int kk = 0; kk < 2; ++kk) {
      bf16x8 a[4], b[4];
      #pragma unroll
      for (int m = 0; m < 4; ++m) {
        int row = wr * 64 + m * 16 + (lane & 15);
        int cb = (kk * 64 + ((lane >> 4) * 16)) ^ ((row & 7) << 4);
        a[m] = *(const bf16x8*)((const char*)As + row * 128 + cb);
      }
      #pragma unroll
      for (int n = 0; n < 4; ++n) {
        int row = wc * 64 + n * 16 + (lane & 15);
        int cb = (kk * 64 + ((lane >> 4) * 16)) ^ ((row & 7) << 4);
        b[n] = *(const bf16x8*)((const char*)Bs + row * 128 + cb);
      }
      #pragma unroll
      for (int m = 0; m < 4; ++m)
        #pragma unroll
        for (int n = 0; n < 4; ++n)
          acc[m][n] = __builtin_amdgcn_mfma_f32_16x16x32_bf16(a[m], b[n], acc[m][n], 0, 0, 0);
    }
  }

  float xv[16], yv[4];
  #pragma unroll
  for (int m = 0; m < 4; ++m)
    #pragma unroll
    for (int r = 0; r < 4; ++r)
      xv[m * 4 + r] = xx[bi + wr * 64 + m * 16 + (lane >> 4) * 4 + r];
  #pragma unroll
  for (int n = 0; n < 4; ++n)
    yv[n] = yy[bj + wc * 64 + n * 16 + (lane & 15)];

  float lsum = 0.f;
  #pragma unroll
  for (int m = 0; m < 4; ++m)
    #pragma unroll
    for (int n = 0; n < 4; ++n)
      #pragma unroll
      for (int r = 0; r < 4; ++r) {
        float d2 = xv[m * 4 + r] + yv[n] - 2.f * acc[m][n][r];
        lsum += sqrtf(fmaxf(d2, 0.f));
      }
  WREDUCE(lsum);
  if (lane == 0) red[wid] = lsum;
  __syncthreads();
  if (tid == 0) atomicAdd(meanacc, (double)(red[0] + red[1] + red[2] + red[3]));
}

// ---------------- dist+exp GEMM: 512 threads / 8 waves (acc[2][4] = 32 AGPR) ----------------
__global__ __launch_bounds__(512) void k_diste(
    const unsigned short* __restrict__ xb, const unsigned short* __restrict__ yb,
    const float* __restrict__ xx, const float* __restrict__ yy,
    const double* __restrict__ meanacc, unsigned char* __restrict__ ebuf,
    float* __restrict__ cs_part) {
  __shared__ __align__(16) char lds[32768];   // As 16K + Bs 16K ; epilogue: etile 128x128 fp16
  unsigned short* As = (unsigned short*)lds;
  unsigned short* Bs = (unsigned short*)(lds + 16384);
  const int bid = blockIdx.x;
  const int xcd = bid & 7, lcl = bid >> 3;
  const int jb = xcd * 8 + (lcl & 7), ib = lcl >> 3;
  const int bj = jb * 128;
  const int bi = ib * 128;
  const int tid = threadIdx.x;
  const int lane = tid & 63, wid = tid >> 6;
  const int wr = wid >> 1, wc = wid & 1;   // 4 x 2 wave grid: wave tile 32 rows x 64 cols
  f32x4 acc[2][4];
  #pragma unroll
  for (int m = 0; m < 2; ++m)
    #pragma unroll
    for (int n = 0; n < 4; ++n) acc[m][n] = (f32x4){0.f, 0.f, 0.f, 0.f};

  for (int k0 = 0; k0 < DIM; k0 += 64) {
    __syncthreads();
    #pragma unroll
    for (int it = 0; it < 2; ++it) {
      int L = it * 512 + tid;
      int cb = (L & 7) * 16;
      int row = L >> 3;
      int cbs = cb ^ ((row & 7) << 4);
      gload_lds16(xb + (size_t)(bi + row) * DIM + k0 + (cbs >> 1), (char*)As + L * 16);
      gload_lds16(yb + (size_t)(bj + row) * DIM + k0 + (cbs >> 1), (char*)Bs + L * 16);
    }
    __syncthreads();
    #pragma unroll
    for (int kk = 0; kk < 2; ++kk) {
      bf16x8 a[2], b[4];
      #pragma unroll
      for (int m = 0; m < 2; ++m) {
        int row = wr * 32 + m * 16 + (lane & 15);
        int cb = (kk * 64 + ((lane >> 4) * 16)) ^ ((row & 7) << 4);
        a[m] = *(const bf16x8*)((const char*)As + row * 128 + cb);
      }
      #pragma unroll
      for (int n = 0; n < 4; ++n) {
        int row = wc * 64 + n * 16 + (lane & 15);
        int cb = (kk * 64 + ((lane >> 4) * 16)) ^ ((row & 7) << 4);
        b[n] = *(const bf16x8*)((const char*)Bs + row * 128 + cb);
      }
      #pragma unroll
      for (int m = 0; m < 2; ++m)
        #pragma unroll
        for (int n = 0; n < 4; ++n)
          acc[m][n] = __builtin_amdgcn_mfma_f32_16x16x32_bf16(a[m], b[n], acc[m][n], 0, 0, 0);
    }
  }

  const float md = (float)(meanacc[0] * MEAN_DIV);
  const float ia2 = 1.f / (0.2f * md);
  float xv[8], yv[4];
  #pragma unroll
  for (int m = 0; m < 2; ++m)
    #pragma unroll
    for (int r = 0; r < 4; ++r)
      xv[m * 4 + r] = xx[bi + wr * 32 + m * 16 + (lane >> 4) * 4 + r];
  #pragma unroll
  for (int n = 0; n < 4; ++n)
    yv[n] = yy[bj + wc * 64 + n * 16 + (lane & 15)];

  const bool hasdiag = (bi == bj);   // diag only when block row == block col (neg half)
  __syncthreads();  // all waves done reading As/Bs; LDS becomes etile (128 rows x 256 B, XOR-swizzled)

  half2v cq4[4] = {}, cq2[4] = {}, cq1[4] = {};
  #pragma unroll
  for (int m = 0; m < 2; ++m) {
    const int r0 = wr * 32 + m * 16 + (lane >> 4) * 4;
    #pragma unroll
    for (int n = 0; n < 4; ++n) {
      const int col = wc * 64 + n * 16 + (lane & 15);
      float q[4];
      #pragma unroll
      for (int r = 0; r < 4; ++r) {
        float d2 = xv[m * 4 + r] + yv[n] - 2.f * acc[m][n][r];
        float d = sqrtf(fmaxf(d2, 0.f));
        q[r] = __expf(fmaf(d, -ia2, LN128));   // ehat = 128*exp(-d*ia2)
      }
      if (hasdiag) {
        #pragma unroll
        for (int r = 0; r < 4; ++r)
          if (r0 + r == col) q[r] = 0.f;
      }
      half2v p01 = cvt_pk(q[0], q[1]);
      half2v p23 = cvt_pk(q[2], q[3]);
      half2v q2a = p01 * p01, q2b = p23 * p23;
      half2v q4a = q2a * q2a, q4b = q2b * q2b;
      cq1[n] += p01; cq1[n] += p23;
      cq2[n] += q2a; cq2[n] += q2b;
      cq4[n] += q4a; cq4[n] += q4b;
      *(_Float16*)(lds + (r0 + 0) * 256 + ((col * 2) ^ (((r0 + 0) & 7) << 4))) = p01[0];
      *(_Float16*)(lds + (r0 + 1) * 256 + ((col * 2) ^ (((r0 + 1) & 7) << 4))) = p01[1];
      *(_Float16*)(lds + (r0 + 2) * 256 + ((col * 2) ^ (((r0 + 2) & 7) << 4))) = p23[0];
      *(_Float16*)(lds + (r0 + 3) * 256 + ((col * 2) ^ (((r0 + 3) & 7) << 4))) = p23[1];
    }
  }
  // reduce col partials (f32) across the 4 lane-groups; per-(rowblock x wave-row) slab
  float csf[3][4];
  #pragma unroll
  for (int n = 0; n < 4; ++n) {
    csf[0][n] = (float)cq4[n][0] + (float)cq4[n][1];
    csf[1][n] = (float)cq2[n][0] + (float)cq2[n][1];
    csf[2][n] = (float)cq1[n][0] + (float)cq1[n][1];
  }
  #pragma unroll
  for (int p = 0; p < 3; ++p)
    #pragma unroll
    for (int n = 0; n < 4; ++n) {
      float v = csf[p][n];
      v += __shfl_xor(v, 16); v += __shfl_xor(v, 32);
      csf[p][n] = v;
    }
  if (lane < 16) {
    const int slab = ib * 4 + wr;   // 0..127
    #pragma unroll
    for (int p = 0; p < 3; ++p)
      #pragma unroll
      for (int n = 0; n < 4; ++n)
        cs_part[(size_t)slab * 24576 + p * 8192 + bj + wc * 64 + n * 16 + lane] = csf[p][n];
  }
  __syncthreads();
  // readback: fp16 etile -> fp8, dwordx2 per lane (4 iters x 512 threads)
  #pragma unroll
  for (int it = 0; it < 4; ++it) {
    int chunk = it * 512 + tid;
    int row = chunk >> 4;                  // 16 threads per row
    int cb16 = (chunk & 15) * 16;          // byte offset in fp16 LDS row (256 B)
    half8 h = *(const half8*)(lds + row * 256 + (cb16 ^ ((row & 7) << 4)));
    int w0 = __builtin_amdgcn_cvt_pk_fp8_f32((float)h[0], (float)h[1], 0, false);
    w0 = __builtin_amdgcn_cvt_pk_fp8_f32((float)h[2], (float)h[3], w0, true);
    int w1 = __builtin_amdgcn_cvt_pk_fp8_f32((float)h[4], (float)h[5], 0, false);
    w1 = __builtin_amdgcn_cvt_pk_fp8_f32((float)h[6], (float)h[7], w1, true);
    int2 outv = { w0, w1 };
    *(int2*)(ebuf + (size_t)(bi + row) * DCOLS + bj + (chunk & 15) * 8) = outv;
  }
}

// ---------------- reduce col partials: ich = fp16 rsqrt(colsum-hat) ----------------
__global__ __launch_bounds__(256) void k_csred(
    const float* __restrict__ cs_part, _Float16* __restrict__ ich) {
  int idx = blockIdx.x * 256 + threadIdx.x;   // grid 96 -> 24576
  float s = 0.f;
  #pragma unroll 8
  for (int sl = 0; sl < 128; ++sl) s += cs_part[(size_t)sl * 24576 + idx];
  ich[idx] = (_Float16)rsqrtf(s);
}

// ---------------- row stats: ghat factors per row (block per row, fp8 in) ----------------
__global__ __launch_bounds__(256) void k_rowstat(
    const unsigned char* __restrict__ ebuf, const _Float16* __restrict__ ich,
    float* __restrict__ gtab) {
  __shared__ float red[4][9];
  const int i = blockIdx.x;
  const int t = threadIdx.x;
  const int lane = t & 63, w = t >> 6;
  const unsigned char* erow = ebuf + (size_t)i * DCOLS;
  half8 r4a = {}, r2a = {}, r1a = {};
  half8 sn4 = {}, sn2 = {}, sn1 = {}, sp4 = {}, sp2 = {}, sp1 = {};
  #pragma unroll
  for (int it = 0; it < 4; ++it) {
    int j0 = it * 2048 + t * 8;
    int2 wd = *(const int2*)(erow + j0);
    half8 e = fp8x8_to_h8(wd.x, wd.y);
    half8 e2 = e * e, e4 = e2 * e2;
    half8 c0 = *(const half8*)(ich + j0);
    half8 c1 = *(const half8*)(ich + 8192 + j0);
    half8 c2 = *(const half8*)(ich + 16384 + j0);
    r4a += e4; r2a += e2; r1a += e;
    if (it < 2) { sn4 += e4 * c0; sn2 += e2 * c1; sn1 += e * c2; }
    else        { sp4 += e4 * c0; sp2 += e2 * c1; sp1 += e * c2; }
  }
  float v0 = hsum8(r4a), v1 = hsum8(r2a), v2 = hsum8(r1a);
  float v3 = hsum8(sn4), v4 = hsum8(sn2), v5 = hsum8(sn1);
  float v6 = hsum8(sp4), v7 = hsum8(sp2), v8 = hsum8(sp1);
  WREDUCE(v0); WREDUCE(v1); WREDUCE(v2);
  WREDUCE(v3); WREDUCE(v4); WREDUCE(v5);
  WREDUCE(v6); WREDUCE(v7); WREDUCE(v8);
  if (lane == 0) {
    red[w][0] = v0; red[w][1] = v1; red[w][2] = v2;
    red[w][3] = v3; red[w][4] = v4; red[w][5] = v5;
    red[w][6] = v6; red[w][7] = v7; red[w][8] = v8;
  }
  __syncthreads();
  if (t < 9) red[0][t] = red[0][t] + red[1][t] + red[2][t] + red[3][t];
  __syncthreads();
  if (t < 3) {
    float R = red[0][t], Sn = red[0][3 + t], Sp = red[0][6 + t];
    gtab[i * 8 + t] = -Sp / R;       // factor for neg cols
    gtab[i * 8 + 4 + t] = Sn / R;    // factor for pos cols
  }
}

// ---------------- flash tail: fp8 e -> packed C-tile (fp16) -> f16 MFMA -> fp16 V ----------------
__global__ __launch_bounds__(512) void k_flash(
    const unsigned char* __restrict__ ebuf, const unsigned short* __restrict__ ybt,
    const _Float16* __restrict__ ich, const float* __restrict__ gtab,
    _Float16* __restrict__ vpart) {
  __shared__ __align__(16) char lds[81920];  // Ct 64x128 fp16 (16K) + Bs 256x128 fp16 (64K)
  const int jc = blockIdx.x;        // 0..7  (j-chunk of 1024; <4 = neg half)
  const int rb = blockIdx.y;        // 0..63 (64-row slab)
  const int j0base = jc * 1024;
  const int tid = threadIdx.x;
  const int lane = tid & 63, wid = tid >> 6;
  const int wr = wid >> 2, wc = wid & 3;   // 2 x 4 wave grid over 64 rows x 256 d
  const int crow = tid >> 3;               // C-epilogue: row 0..63
  const int cjA = (tid & 7) * 16;          // 16 j's per thread (2 x half8)
  const float* gp = gtab + (size_t)(rb * 64 + crow) * 8 + (jc < 4 ? 0 : 4);
  const _Float16 g0h = (_Float16)gp[0], g1h = (_Float16)gp[1], g2h = (_Float16)gp[2];
  const half8 g0v = {g0h, g0h, g0h, g0h, g0h, g0h, g0h, g0h};
  const half8 g1v = {g1h, g1h, g1h, g1h, g1h, g1h, g1h, g1h};
  const half8 g2v = {g2h, g2h, g2h, g2h, g2h, g2h, g2h, g2h};
  const unsigned char* erowp = ebuf + (size_t)(rb * 64 + crow) * DCOLS;

  f32x4 acc[2][4];
  #pragma unroll
  for (int m = 0; m < 2; ++m)
    #pragma unroll
    for (int n = 0; n < 4; ++n) acc[m][n] = (f32x4){0.f, 0.f, 0.f, 0.f};

  for (int jt = 0; jt < 8; ++jt) {
    const int j0 = j0base + jt * 128;
    __syncthreads();                       // protect prev-iter LDS reads
    // stage ybt tile [256 d][128 j] fp16 (64 KiB, swizzled dst via pre-swizzled source)
    #pragma unroll
    for (int it = 0; it < 8; ++it) {
      int L = it * 512 + tid;
      int row = L >> 4;                    // 16 x 16-B chunks per 256-B row
      int cb = (L & 15) * 16;
      int cbs = cb ^ ((row & 7) << 4);
      gload_lds16(ybt + (size_t)row * DCOLS + j0 + (cbs >> 1), lds + 16384 + L * 16);
    }
    // C-tile compute: fp8 -> 2 x half8 per thread, ds_write swizzled
    {
      int4 wd = *(const int4*)(erowp + j0 + cjA);
      half8 ea = fp8x8_to_h8(wd.x, wd.y);
      half8 eb = fp8x8_to_h8(wd.z, wd.w);
      #pragma unroll
      for (int u2 = 0; u2 < 2; ++u2) {
        half8 e = u2 ? eb : ea;
        half8 e2 = e * e, e4 = e2 * e2;
        const int joff = cjA + u2 * 8;
        half8 c0 = *(const half8*)(ich + j0 + joff);
        half8 c1 = *(const half8*)(ich + 8192 + j0 + joff);
        half8 c2 = *(const half8*)(ich + 16384 + j0 + joff);
        half8 C8 = (e4 * c0) * g0v + (e2 * c1) * g1v + (e * c2) * g2v;
        *(half8*)(lds + crow * 256 + ((joff * 2) ^ ((crow & 7) << 4))) = C8;
      }
    }
    __syncthreads();                       // drains vmcnt (stage) + lgkm (ds_write)
    #pragma unroll
    for (int kk = 0; kk < 4; ++kk) {
      half8 a[2], b[4];
      #pragma unroll
      for (int m = 0; m < 2; ++m) {
        int row = wr * 32 + m * 16 + (lane & 15);
        int cb = (kk * 64 + ((lane >> 4) * 16)) ^ ((row & 7) << 4);
        a[m] = *(const half8*)(lds + row * 256 + cb);
      }
      #pragma unroll
      for (int n = 0; n < 4; ++n) {
        int row = wc * 64 + n * 16 + (lane & 15);
        int cb = (kk * 64 + ((lane >> 4) * 16)) ^ ((row & 7) << 4);
        b[n] = *(const half8*)(lds + 16384 + row * 256 + cb);
      }
      #pragma unroll
      for (int m = 0; m < 2; ++m)
        #pragma unroll
        for (int n = 0; n < 4; ++n)
          acc[m][n] = __builtin_amdgcn_mfma_f32_16x16x32_f16(a[m], b[n], acc[m][n], 0, 0, 0);
    }
  }
  // write V partial (fp16)
  #pragma unroll
  for (int m = 0; m < 2; ++m)
    #pragma unroll
    for (int n = 0; n < 4; ++n)
      #pragma unroll
      for (int r = 0; r < 4; ++r) {
        int gi = rb * 64 + wr * 32 + m * 16 + (lane >> 4) * 4 + r;
        int gd = wc * 64 + n * 16 + (lane & 15);
        vpart[(size_t)jc * 1048576 + (size_t)gi * 256 + gd] = (_Float16)acc[m][n][r];
      }
}

// ---------------- loss reduction ----------------
__global__ __launch_bounds__(256) void k_loss(
    const _Float16* __restrict__ vpart, float* __restrict__ ploss) {
  const int tid = blockIdx.x * 256 + threadIdx.x;   // grid 512 -> 131072 threads
  const size_t e0 = (size_t)tid * 8;                // 8 elems per thread
  float vv[8] = {0, 0, 0, 0, 0, 0, 0, 0};
  #pragma unroll
  for (int sl = 0; sl < 8; ++sl) {
    half8 h = *(const half8*)(vpart + (size_t)sl * 1048576 + e0);
    #pragma unroll
    for (int u = 0; u < 8; ++u) vv[u] += (float)h[u];
  }
  float s = 0.f;
  #pragma unroll
  for (int u = 0; u < 8; ++u) s += vv[u] * vv[u];
  WREDUCE(s);
  __shared__ float red[4];
  if ((threadIdx.x & 63) == 0) red[threadIdx.x >> 6] = s;
  __syncthreads();
  if (threadIdx.x == 0) ploss[blockIdx.x] = red[0] + red[1] + red[2] + red[3];
}

__global__ __launch_bounds__(256) void k_finish(
    const float* __restrict__ ploss, float* __restrict__ out) {
  float v = ploss[threadIdx.x] + ploss[threadIdx.x + 256];
  WREDUCE(v);
  __shared__ float red[4];
  if ((threadIdx.x & 63) == 0) red[threadIdx.x >> 6] = v;
  __syncthreads();
  if (threadIdx.x == 0)
    out[0] = (float)((double)(red[0] + red[1] + red[2] + red[3]) / 1048576.0);
}

extern "C" void kernel_launch(void* const* d_in, const int* in_sizes, int n_in,
                              void* d_out, int out_size, void* d_ws, size_t ws_size,
                              hipStream_t stream) {
  (void)in_sizes; (void)n_in; (void)out_size; (void)ws_size;
  const float* x    = (const float*)d_in[0];
  const float* ypos = (const float*)d_in[1];
  const float* yneg = (const float*)d_in[2];

  char* ws = (char*)d_ws;
  size_t o = 0;
  unsigned char* dist = (unsigned char*)(ws + o); o += (size_t)NROWS * DCOLS;        // 32 MiB (ehat fp8)
  unsigned short* xb   = (unsigned short*)(ws + o); o += (size_t)NROWS * DIM * 2;    // 2 MiB
  unsigned short* yb   = (unsigned short*)(ws + o); o += (size_t)DCOLS * DIM * 2;    // 4 MiB
  unsigned short* ybt  = (unsigned short*)(ws + o); o += (size_t)DCOLS * DIM * 2;    // 4 MiB (fp16)
  float* xx      = (float*)(ws + o); o += NROWS * 4;
  float* yy      = (float*)(ws + o); o += DCOLS * 4;
  double* meanacc = (double*)(ws + o); o += 256;
  _Float16* ich  = (_Float16*)(ws + o); o += 3 * DCOLS * 2;      // 48 KiB fp16 rsqrt(colsum-hat)
  float* gtab    = (float*)(ws + o); o += (size_t)NROWS * 8 * 4; // 128 KiB
  float* ploss   = (float*)(ws + o); o += 512 * 4;
  // union region (16 MiB): cs_part (12 MiB, dead after csred) aliased with vpart fp16 (16 MiB)
  float* cs_part = (float*)(ws + o);
  _Float16* vpart = (_Float16*)(ws + o); o += (size_t)8 * NROWS * DIM * 2;           // 16 MiB

  hipMemsetAsync(meanacc, 0, 8, stream);
  k_prep<<<3072, 256, 0, stream>>>(x, ypos, yneg, xb, yb, xx, yy);
  k_transpose<<<dim3(128, 4), 256, 0, stream>>>(ypos, yneg, ybt);
  k_mean<<<dim3(32, 4), 256, 0, stream>>>(xb, yb, xx, yy, meanacc);
  k_diste<<<2048, 512, 0, stream>>>(xb, yb, xx, yy, meanacc, dist, cs_part);
  k_csred<<<96, 256, 0, stream>>>(cs_part, ich);
  k_rowstat<<<4096, 256, 0, stream>>>(dist, ich, gtab);
  k_flash<<<dim3(8, 64), 512, 0, stream>>>(dist, ybt, ich, gtab, vpart);
  k_loss<<<512, 256, 0, stream>>>(vpart, ploss);
  k_finish<<<1, 256, 0, stream>>>(ploss, (float*)d_out);
}

// Round 18
// 130.209 us; speedup vs baseline: 1.0332x; 1.0332x over previous
//
#include <hip/hip_runtime.h>

#define NROWS 4096
#define DCOLS 8192
#define DIM   256
#define NHALF 4096

typedef __attribute__((ext_vector_type(8))) short bf16x8;
typedef __attribute__((ext_vector_type(4))) float f32x4;
typedef __attribute__((ext_vector_type(4))) unsigned short ushort4v;
typedef __attribute__((ext_vector_type(2))) _Float16 half2v;
typedef __attribute__((ext_vector_type(4))) _Float16 half4v;
typedef __attribute__((ext_vector_type(8))) _Float16 half8;

#define LN128 4.852030263919617f
// mean sampled over 512 x-rows x 4096 pos cols
#define MEAN_DIV (1.0 / 2097152.0)

static __device__ __forceinline__ unsigned short f2bf(float f) {
  union { float f; unsigned int i; } v; v.f = f;
  unsigned int x = v.i;
  return (unsigned short)((x + 0x7fffu + ((x >> 16) & 1u)) >> 16);
}

static __device__ __forceinline__ half2v cvt_pk(float a, float b) {
  return __builtin_bit_cast(half2v, __builtin_amdgcn_cvt_pkrtz(a, b));
}

// 8 fp8 (two dwords) -> half8 via f32
static __device__ __forceinline__ half8 fp8x8_to_h8(int lo, int hi) {
  auto p0 = __builtin_amdgcn_cvt_pk_f32_fp8(lo, false);
  auto p1 = __builtin_amdgcn_cvt_pk_f32_fp8(lo, true);
  auto p2 = __builtin_amdgcn_cvt_pk_f32_fp8(hi, false);
  auto p3 = __builtin_amdgcn_cvt_pk_f32_fp8(hi, true);
  half2v h0 = cvt_pk(p0[0], p0[1]);
  half2v h1 = cvt_pk(p1[0], p1[1]);
  half2v h2 = cvt_pk(p2[0], p2[1]);
  half2v h3 = cvt_pk(p3[0], p3[1]);
  return (half8){h0[0], h0[1], h1[0], h1[1], h2[0], h2[1], h3[0], h3[1]};
}

static __device__ __forceinline__ void gload_lds16(const void* g, void* l) {
  __builtin_amdgcn_global_load_lds(
      (const __attribute__((address_space(1))) void*)g,
      (__attribute__((address_space(3))) void*)l, 16, 0, 0);
}

static __device__ __forceinline__ float hsum8(half8 v) {
  float s = 0.f;
  #pragma unroll
  for (int u = 0; u < 8; ++u) s += (float)v[u];
  return s;
}

#define WREDUCE(v) { v += __shfl_xor(v, 1); v += __shfl_xor(v, 2); v += __shfl_xor(v, 4); \
                     v += __shfl_xor(v, 8); v += __shfl_xor(v, 16); v += __shfl_xor(v, 32); }

// ---------------- prep: bf16 convert + row norms (wave per row, float4) ----------------
__global__ __launch_bounds__(256) void k_prep(
    const float* __restrict__ x, const float* __restrict__ ypos,
    const float* __restrict__ yneg, unsigned short* __restrict__ xb,
    unsigned short* __restrict__ yb, float* __restrict__ xx, float* __restrict__ yy) {
  const int lane = threadIdx.x & 63, w = threadIdx.x >> 6;
  const int b = blockIdx.x * 4 + w;   // 0..12287
  const float* src; unsigned short* dst; float* nrm;
  if (b < 4096)      { src = x + (size_t)b * DIM;             dst = xb + (size_t)b * DIM;            nrm = xx + b; }
  else if (b < 8192) { int r = b - 4096; src = yneg + (size_t)r * DIM; dst = yb + (size_t)r * DIM;   nrm = yy + r; }
  else               { int r = b - 8192; src = ypos + (size_t)r * DIM; dst = yb + (size_t)(NHALF + r) * DIM; nrm = yy + NHALF + r; }
  float4 v = *(const float4*)(src + lane * 4);
  ushort4v ov = { f2bf(v.x), f2bf(v.y), f2bf(v.z), f2bf(v.w) };
  *(ushort4v*)(dst + lane * 4) = ov;
  float s = v.x * v.x + v.y * v.y + v.z * v.z + v.w * v.w;
  WREDUCE(s);
  if (lane == 0) nrm[0] = s;
}

// ---------------- transpose y f32 (8192x256) -> ybt fp16 (256x8192) ----------------
__global__ __launch_bounds__(256) void k_transpose(
    const float* __restrict__ ypos, const float* __restrict__ yneg,
    unsigned short* __restrict__ ybt) {
  __shared__ unsigned short tile[64][68];
  int r0 = blockIdx.x * 64;   // yb-row space: 0-4095 neg, 4096-8191 pos
  int c0 = blockIdx.y * 64;
  const float* src = (r0 < NHALF) ? (yneg + (size_t)r0 * DIM)
                                  : (ypos + (size_t)(r0 - NHALF) * DIM);
  int tx = threadIdx.x & 63, ty = threadIdx.x >> 6;
  #pragma unroll
  for (int it = 0; it < 16; ++it) {
    int r = it * 4 + ty;
    _Float16 h = (_Float16)src[(size_t)r * DIM + c0 + tx];
    tile[r][tx] = __builtin_bit_cast(unsigned short, h);
  }
  __syncthreads();
  #pragma unroll
  for (int it = 0; it < 16; ++it) {
    int c = it * 4 + ty;
    ybt[(size_t)(c0 + c) * DCOLS + r0 + tx] = tile[tx][c];
  }
}

// ---------------- mean GEMM: sampled (512 x-rows) x pos half, no stores ----------------
__global__ __launch_bounds__(256) void k_mean(
    const unsigned short* __restrict__ xb, const unsigned short* __restrict__ yb,
    const float* __restrict__ xx, const float* __restrict__ yy,
    double* __restrict__ meanacc) {
  __shared__ unsigned short As[128 * 64];
  __shared__ unsigned short Bs[128 * 64];
  __shared__ float red[4];
  const int bj = NHALF + blockIdx.x * 128;   // pos half
  const int bi = blockIdx.y * 128;           // rows 0..511
  const int tid = threadIdx.x;
  const int lane = tid & 63, wid = tid >> 6;
  const int wr = wid >> 1, wc = wid & 1;
  f32x4 acc[4][4];
  #pragma unroll
  for (int m = 0; m < 4; ++m)
    #pragma unroll
    for (int n = 0; n < 4; ++n) acc[m][n] = (f32x4){0.f, 0.f, 0.f, 0.f};

  for (int k0 = 0; k0 < DIM; k0 += 64) {
    __syncthreads();
    #pragma unroll
    for (int it = 0; it < 4; ++it) {
      int L = it * 256 + tid;
      int row = L >> 3;
      int cb = (L & 7) * 16;
      int cbs = cb ^ ((row & 7) << 4);
      gload_lds16(xb + (size_t)(bi + row) * DIM + k0 + (cbs >> 1), (char*)As + L * 16);
      gload_lds16(yb + (size_t)(bj + row) * DIM + k0 + (cbs >> 1), (char*)Bs + L * 16);
    }
    __syncthreads();
    #pragma unroll
    for (int kk = 0; kk < 2; ++kk) {
      bf16x8 a[4], b[4];
      #pragma unroll
      for (int m = 0; m < 4; ++m) {
        int row = wr * 64 + m * 16 + (lane & 15);
        int cb = (kk * 64 + ((lane >> 4) * 16)) ^ ((row & 7) << 4);
        a[m] = *(const bf16x8*)((const char*)As + row * 128 + cb);
      }
      #pragma unroll
      for (int n = 0; n < 4; ++n) {
        int row = wc * 64 + n * 16 + (lane & 15);
        int cb = (kk * 64 + ((lane >> 4) * 16)) ^ ((row & 7) << 4);
        b[n] = *(const bf16x8*)((const char*)Bs + row * 128 + cb);
      }
      #pragma unroll
      for (int m = 0; m < 4; ++m)
        #pragma unroll
        for (int n = 0; n < 4; ++n)
          acc[m][n] = __builtin_amdgcn_mfma_f32_16x16x32_bf16(a[m], b[n], acc[m][n], 0, 0, 0);
    }
  }

  float xv[16], yv[4];
  #pragma unroll
  for (int m = 0; m < 4; ++m)
    #pragma unroll
    for (int r = 0; r < 4; ++r)
      xv[m * 4 + r] = xx[bi + wr * 64 + m * 16 + (lane >> 4) * 4 + r];
  #pragma unroll
  for (int n = 0; n < 4; ++n)
    yv[n] = yy[bj + wc * 64 + n * 16 + (lane & 15)];

  float lsum = 0.f;
  #pragma unroll
  for (int m = 0; m < 4; ++m)
    #pragma unroll
    for (int n = 0; n < 4; ++n)
      #pragma unroll
      for (int r = 0; r < 4; ++r) {
        float d2 = xv[m * 4 + r] + yv[n] - 2.f * acc[m][n][r];
        lsum += sqrtf(fmaxf(d2, 0.f));
      }
  WREDUCE(lsum);
  if (lane == 0) red[wid] = lsum;
  __syncthreads();
  if (tid == 0) atomicAdd(meanacc, (double)(red[0] + red[1] + red[2] + red[3]));
}

// ---------------- dist+exp GEMM: 8 waves, LDS cst reduce -> 32 cs slabs ----------------
__global__ __launch_bounds__(512) void k_diste(
    const unsigned short* __restrict__ xb, const unsigned short* __restrict__ yb,
    const float* __restrict__ xx, const float* __restrict__ yy,
    const double* __restrict__ meanacc, unsigned char* __restrict__ ebuf,
    float* __restrict__ cs_part) {
  // GEMM: As 16K + Bs 16K. Epilogue: etile 32K (fp16, swizzled) + cst 6K
  __shared__ __align__(16) char lds[38912];
  unsigned short* As = (unsigned short*)lds;
  unsigned short* Bs = (unsigned short*)(lds + 16384);
  float* cst = (float*)(lds + 32768);   // [4 wr][3 p][128 col]
  const int bid = blockIdx.x;
  const int xcd = bid & 7, lcl = bid >> 3;
  const int jb = xcd * 8 + (lcl & 7), ib = lcl >> 3;
  const int bj = jb * 128;
  const int bi = ib * 128;
  const int tid = threadIdx.x;
  const int lane = tid & 63, wid = tid >> 6;
  const int wr = wid >> 1, wc = wid & 1;   // 4 x 2 wave grid: wave tile 32 rows x 64 cols
  f32x4 acc[2][4];
  #pragma unroll
  for (int m = 0; m < 2; ++m)
    #pragma unroll
    for (int n = 0; n < 4; ++n) acc[m][n] = (f32x4){0.f, 0.f, 0.f, 0.f};

  for (int k0 = 0; k0 < DIM; k0 += 64) {
    __syncthreads();
    #pragma unroll
    for (int it = 0; it < 2; ++it) {
      int L = it * 512 + tid;
      int cb = (L & 7) * 16;
      int row = L >> 3;
      int cbs = cb ^ ((row & 7) << 4);
      gload_lds16(xb + (size_t)(bi + row) * DIM + k0 + (cbs >> 1), (char*)As + L * 16);
      gload_lds16(yb + (size_t)(bj + row) * DIM + k0 + (cbs >> 1), (char*)Bs + L * 16);
    }
    __syncthreads();
    #pragma unroll
    for (int kk = 0; kk < 2; ++kk) {
      bf16x8 a[2], b[4];
      #pragma unroll
      for (int m = 0; m < 2; ++m) {
        int row = wr * 32 + m * 16 + (lane & 15);
        int cb = (kk * 64 + ((lane >> 4) * 16)) ^ ((row & 7) << 4);
        a[m] = *(const bf16x8*)((const char*)As + row * 128 + cb);
      }
      #pragma unroll
      for (int n = 0; n < 4; ++n) {
        int row = wc * 64 + n * 16 + (lane & 15);
        int cb = (kk * 64 + ((lane >> 4) * 16)) ^ ((row & 7) << 4);
        b[n] = *(const bf16x8*)((const char*)Bs + row * 128 + cb);
      }
      #pragma unroll
      for (int m = 0; m < 2; ++m)
        #pragma unroll
        for (int n = 0; n < 4; ++n)
          acc[m][n] = __builtin_amdgcn_mfma_f32_16x16x32_bf16(a[m], b[n], acc[m][n], 0, 0, 0);
    }
  }

  const float md = (float)(meanacc[0] * MEAN_DIV);
  const float ia2 = 1.f / (0.2f * md);
  float xv[8], yv[4];
  #pragma unroll
  for (int m = 0; m < 2; ++m)
    #pragma unroll
    for (int r = 0; r < 4; ++r)
      xv[m * 4 + r] = xx[bi + wr * 32 + m * 16 + (lane >> 4) * 4 + r];
  #pragma unroll
  for (int n = 0; n < 4; ++n)
    yv[n] = yy[bj + wc * 64 + n * 16 + (lane & 15)];

  const bool hasdiag = (bi == bj);   // diag only when block row == block col (neg half)
  __syncthreads();  // all waves done reading As/Bs; LDS becomes etile + cst

  half2v cq4[4] = {}, cq2[4] = {}, cq1[4] = {};
  #pragma unroll
  for (int m = 0; m < 2; ++m) {
    const int r0 = wr * 32 + m * 16 + (lane >> 4) * 4;
    #pragma unroll
    for (int n = 0; n < 4; ++n) {
      const int col = wc * 64 + n * 16 + (lane & 15);
      float q[4];
      #pragma unroll
      for (int r = 0; r < 4; ++r) {
        float d2 = xv[m * 4 + r] + yv[n] - 2.f * acc[m][n][r];
        float d = sqrtf(fmaxf(d2, 0.f));
        q[r] = __expf(fmaf(d, -ia2, LN128));   // ehat = 128*exp(-d*ia2)
      }
      if (hasdiag) {
        #pragma unroll
        for (int r = 0; r < 4; ++r)
          if (r0 + r == col) q[r] = 0.f;
      }
      half2v p01 = cvt_pk(q[0], q[1]);
      half2v p23 = cvt_pk(q[2], q[3]);
      half2v q2a = p01 * p01, q2b = p23 * p23;
      half2v q4a = q2a * q2a, q4b = q2b * q2b;
      cq1[n] += p01; cq1[n] += p23;
      cq2[n] += q2a; cq2[n] += q2b;
      cq4[n] += q4a; cq4[n] += q4b;
      *(_Float16*)(lds + (r0 + 0) * 256 + ((col * 2) ^ (((r0 + 0) & 7) << 4))) = p01[0];
      *(_Float16*)(lds + (r0 + 1) * 256 + ((col * 2) ^ (((r0 + 1) & 7) << 4))) = p01[1];
      *(_Float16*)(lds + (r0 + 2) * 256 + ((col * 2) ^ (((r0 + 2) & 7) << 4))) = p23[0];
      *(_Float16*)(lds + (r0 + 3) * 256 + ((col * 2) ^ (((r0 + 3) & 7) << 4))) = p23[1];
    }
  }
  // reduce col partials (f32) across the 4 lane-groups; stage per-wave into LDS cst
  float csf[3][4];
  #pragma unroll
  for (int n = 0; n < 4; ++n) {
    csf[0][n] = (float)cq4[n][0] + (float)cq4[n][1];
    csf[1][n] = (float)cq2[n][0] + (float)cq2[n][1];
    csf[2][n] = (float)cq1[n][0] + (float)cq1[n][1];
  }
  #pragma unroll
  for (int p = 0; p < 3; ++p)
    #pragma unroll
    for (int n = 0; n < 4; ++n) {
      float v = csf[p][n];
      v += __shfl_xor(v, 16); v += __shfl_xor(v, 32);
      csf[p][n] = v;
    }
  if (lane < 16) {
    #pragma unroll
    for (int p = 0; p < 3; ++p)
      #pragma unroll
      for (int n = 0; n < 4; ++n)
        cst[wr * 384 + p * 128 + wc * 64 + n * 16 + lane] = csf[p][n];
  }
  __syncthreads();
  // cross-wave cst reduce -> one cs slab per ib (32 slabs total)
  if (tid < 384) {
    int p = tid >> 7, col = tid & 127;
    float s = cst[p * 128 + col] + cst[384 + p * 128 + col]
            + cst[768 + p * 128 + col] + cst[1152 + p * 128 + col];
    cs_part[(size_t)ib * 24576 + p * 8192 + bj + col] = s;
  }
  // readback: fp16 etile -> fp8, dwordx2 per lane (4 iters x 512 threads)
  #pragma unroll
  for (int it = 0; it < 4; ++it) {
    int chunk = it * 512 + tid;
    int row = chunk >> 4;                  // 16 threads per row
    int cb16 = (chunk & 15) * 16;          // byte offset in fp16 LDS row (256 B)
    half8 h = *(const half8*)(lds + row * 256 + (cb16 ^ ((row & 7) << 4)));
    int w0 = __builtin_amdgcn_cvt_pk_fp8_f32((float)h[0], (float)h[1], 0, false);
    w0 = __builtin_amdgcn_cvt_pk_fp8_f32((float)h[2], (float)h[3], w0, true);
    int w1 = __builtin_amdgcn_cvt_pk_fp8_f32((float)h[4], (float)h[5], 0, false);
    w1 = __builtin_amdgcn_cvt_pk_fp8_f32((float)h[6], (float)h[7], w1, true);
    int2 outv = { w0, w1 };
    *(int2*)(ebuf + (size_t)(bi + row) * DCOLS + bj + (chunk & 15) * 8) = outv;
  }
}

// ---------------- reduce col partials: ich = fp16 rsqrt(colsum-hat) ----------------
__global__ __launch_bounds__(256) void k_csred(
    const float* __restrict__ cs_part, _Float16* __restrict__ ich) {
  int idx = blockIdx.x * 256 + threadIdx.x;   // grid 96 -> 24576
  float s = 0.f;
  #pragma unroll 8
  for (int sl = 0; sl < 32; ++sl) s += cs_part[(size_t)sl * 24576 + idx];
  ich[idx] = (_Float16)rsqrtf(s);
}

// ---------------- row stats: ghat factors per row (block per row, fp8 in) ----------------
__global__ __launch_bounds__(256) void k_rowstat(
    const unsigned char* __restrict__ ebuf, const _Float16* __restrict__ ich,
    float* __restrict__ gtab) {
  __shared__ float red[4][9];
  const int i = blockIdx.x;
  const int t = threadIdx.x;
  const int lane = t & 63, w = t >> 6;
  const unsigned char* erow = ebuf + (size_t)i * DCOLS;
  half8 r4a = {}, r2a = {}, r1a = {};
  half8 sn4 = {}, sn2 = {}, sn1 = {}, sp4 = {}, sp2 = {}, sp1 = {};
  #pragma unroll
  for (int it = 0; it < 4; ++it) {
    int j0 = it * 2048 + t * 8;
    int2 wd = *(const int2*)(erow + j0);
    half8 e = fp8x8_to_h8(wd.x, wd.y);
    half8 e2 = e * e, e4 = e2 * e2;
    half8 c0 = *(const half8*)(ich + j0);
    half8 c1 = *(const half8*)(ich + 8192 + j0);
    half8 c2 = *(const half8*)(ich + 16384 + j0);
    r4a += e4; r2a += e2; r1a += e;
    if (it < 2) { sn4 += e4 * c0; sn2 += e2 * c1; sn1 += e * c2; }
    else        { sp4 += e4 * c0; sp2 += e2 * c1; sp1 += e * c2; }
  }
  float v0 = hsum8(r4a), v1 = hsum8(r2a), v2 = hsum8(r1a);
  float v3 = hsum8(sn4), v4 = hsum8(sn2), v5 = hsum8(sn1);
  float v6 = hsum8(sp4), v7 = hsum8(sp2), v8 = hsum8(sp1);
  WREDUCE(v0); WREDUCE(v1); WREDUCE(v2);
  WREDUCE(v3); WREDUCE(v4); WREDUCE(v5);
  WREDUCE(v6); WREDUCE(v7); WREDUCE(v8);
  if (lane == 0) {
    red[w][0] = v0; red[w][1] = v1; red[w][2] = v2;
    red[w][3] = v3; red[w][4] = v4; red[w][5] = v5;
    red[w][6] = v6; red[w][7] = v7; red[w][8] = v8;
  }
  __syncthreads();
  if (t < 9) red[0][t] = red[0][t] + red[1][t] + red[2][t] + red[3][t];
  __syncthreads();
  if (t < 3) {
    float R = red[0][t], Sn = red[0][3 + t], Sp = red[0][6 + t];
    gtab[i * 8 + t] = -Sp / R;       // factor for neg cols
    gtab[i * 8 + 4 + t] = Sn / R;    // factor for pos cols
  }
}

// ---------------- flash tail: fp8 e -> packed C-tile (fp16) -> f16 MFMA -> fp16 V ----------------
__global__ __launch_bounds__(512) void k_flash(
    const unsigned char* __restrict__ ebuf, const unsigned short* __restrict__ ybt,
    const _Float16* __restrict__ ich, const float* __restrict__ gtab,
    _Float16* __restrict__ vpart) {
  __shared__ __align__(16) char lds[81920];  // Ct 64x128 fp16 (16K) + Bs 256x128 fp16 (64K)
  const int jc = blockIdx.x;        // 0..7  (j-chunk of 1024; <4 = neg half)
  const int rb = blockIdx.y;        // 0..63 (64-row slab)
  const int j0base = jc * 1024;
  const int tid = threadIdx.x;
  const int lane = tid & 63, wid = tid >> 6;
  const int wr = wid >> 2, wc = wid & 3;   // 2 x 4 wave grid over 64 rows x 256 d
  const int crow = tid >> 3;               // C-epilogue: row 0..63
  const int cjA = (tid & 7) * 16;          // 16 j's per thread (2 x half8)
  const float* gp = gtab + (size_t)(rb * 64 + crow) * 8 + (jc < 4 ? 0 : 4);
  const _Float16 g0h = (_Float16)gp[0], g1h = (_Float16)gp[1], g2h = (_Float16)gp[2];
  const half8 g0v = {g0h, g0h, g0h, g0h, g0h, g0h, g0h, g0h};
  const half8 g1v = {g1h, g1h, g1h, g1h, g1h, g1h, g1h, g1h};
  const half8 g2v = {g2h, g2h, g2h, g2h, g2h, g2h, g2h, g2h};
  const unsigned char* erowp = ebuf + (size_t)(rb * 64 + crow) * DCOLS;

  f32x4 acc[2][4];
  #pragma unroll
  for (int m = 0; m < 2; ++m)
    #pragma unroll
    for (int n = 0; n < 4; ++n) acc[m][n] = (f32x4){0.f, 0.f, 0.f, 0.f};

  for (int jt = 0; jt < 8; ++jt) {
    const int j0 = j0base + jt * 128;
    __syncthreads();                       // protect prev-iter LDS reads
    // stage ybt tile [256 d][128 j] fp16 (64 KiB, swizzled dst via pre-swizzled source)
    #pragma unroll
    for (int it = 0; it < 8; ++it) {
      int L = it * 512 + tid;
      int row = L >> 4;                    // 16 x 16-B chunks per 256-B row
      int cb = (L & 15) * 16;
      int cbs = cb ^ ((row & 7) << 4);
      gload_lds16(ybt + (size_t)row * DCOLS + j0 + (cbs >> 1), lds + 16384 + L * 16);
    }
    // C-tile compute: fp8 -> 2 x half8 per thread, ds_write swizzled
    {
      int4 wd = *(const int4*)(erowp + j0 + cjA);
      half8 ea = fp8x8_to_h8(wd.x, wd.y);
      half8 eb = fp8x8_to_h8(wd.z, wd.w);
      #pragma unroll
      for (int u2 = 0; u2 < 2; ++u2) {
        half8 e = u2 ? eb : ea;
        half8 e2 = e * e, e4 = e2 * e2;
        const int joff = cjA + u2 * 8;
        half8 c0 = *(const half8*)(ich + j0 + joff);
        half8 c1 = *(const half8*)(ich + 8192 + j0 + joff);
        half8 c2 = *(const half8*)(ich + 16384 + j0 + joff);
        half8 C8 = (e4 * c0) * g0v + (e2 * c1) * g1v + (e * c2) * g2v;
        *(half8*)(lds + crow * 256 + ((joff * 2) ^ ((crow & 7) << 4))) = C8;
      }
    }
    __syncthreads();                       // drains vmcnt (stage) + lgkm (ds_write)
    #pragma unroll
    for (int kk = 0; kk < 4; ++kk) {
      half8 a[2], b[4];
      #pragma unroll
      for (int m = 0; m < 2; ++m) {
        int row = wr * 32 + m * 16 + (lane & 15);
        int cb = (kk * 64 + ((lane >> 4) * 16)) ^ ((row & 7) << 4);
        a[m] = *(const half8*)(lds + row * 256 + cb);
      }
      #pragma unroll
      for (int n = 0; n < 4; ++n) {
        int row = wc * 64 + n * 16 + (lane & 15);
        int cb = (kk * 64 + ((lane >> 4) * 16)) ^ ((row & 7) << 4);
        b[n] = *(const half8*)(lds + 16384 + row * 256 + cb);
      }
      #pragma unroll
      for (int m = 0; m < 2; ++m)
        #pragma unroll
        for (int n = 0; n < 4; ++n)
          acc[m][n] = __builtin_amdgcn_mfma_f32_16x16x32_f16(a[m], b[n], acc[m][n], 0, 0, 0);
    }
  }
  // write V partial (fp16)
  #pragma unroll
  for (int m = 0; m < 2; ++m)
    #pragma unroll
    for (int n = 0; n < 4; ++n)
      #pragma unroll
      for (int r = 0; r < 4; ++r) {
        int gi = rb * 64 + wr * 32 + m * 16 + (lane >> 4) * 4 + r;
        int gd = wc * 64 + n * 16 + (lane & 15);
        vpart[(size_t)jc * 1048576 + (size_t)gi * 256 + gd] = (_Float16)acc[m][n][r];
      }
}

// ---------------- loss reduction ----------------
__global__ __launch_bounds__(256) void k_loss(
    const _Float16* __restrict__ vpart, float* __restrict__ ploss) {
  const int tid = blockIdx.x * 256 + threadIdx.x;   // grid 512 -> 131072 threads
  const size_t e0 = (size_t)tid * 8;                // 8 elems per thread
  float vv[8] = {0, 0, 0, 0, 0, 0, 0, 0};
  #pragma unroll
  for (int sl = 0; sl < 8; ++sl) {
    half8 h = *(const half8*)(vpart + (size_t)sl * 1048576 + e0);
    #pragma unroll
    for (int u = 0; u < 8; ++u) vv[u] += (float)h[u];
  }
  float s = 0.f;
  #pragma unroll
  for (int u = 0; u < 8; ++u) s += vv[u] * vv[u];
  WREDUCE(s);
  __shared__ float red[4];
  if ((threadIdx.x & 63) == 0) red[threadIdx.x >> 6] = s;
  __syncthreads();
  if (threadIdx.x == 0) ploss[blockIdx.x] = red[0] + red[1] + red[2] + red[3];
}

__global__ __launch_bounds__(256) void k_finish(
    const float* __restrict__ ploss, float* __restrict__ out) {
  float v = ploss[threadIdx.x] + ploss[threadIdx.x + 256];
  WREDUCE(v);
  __shared__ float red[4];
  if ((threadIdx.x & 63) == 0) red[threadIdx.x >> 6] = v;
  __syncthreads();
  if (threadIdx.x == 0)
    out[0] = (float)((double)(red[0] + red[1] + red[2] + red[3]) / 1048576.0);
}

extern "C" void kernel_launch(void* const* d_in, const int* in_sizes, int n_in,
                              void* d_out, int out_size, void* d_ws, size_t ws_size,
                              hipStream_t stream) {
  (void)in_sizes; (void)n_in; (void)out_size; (void)ws_size;
  const float* x    = (const float*)d_in[0];
  const float* ypos = (const float*)d_in[1];
  const float* yneg = (const float*)d_in[2];

  char* ws = (char*)d_ws;
  size_t o = 0;
  unsigned char* dist = (unsigned char*)(ws + o); o += (size_t)NROWS * DCOLS;        // 32 MiB (ehat fp8)
  unsigned short* xb   = (unsigned short*)(ws + o); o += (size_t)NROWS * DIM * 2;    // 2 MiB
  unsigned short* yb   = (unsigned short*)(ws + o); o += (size_t)DCOLS * DIM * 2;    // 4 MiB
  unsigned short* ybt  = (unsigned short*)(ws + o); o += (size_t)DCOLS * DIM * 2;    // 4 MiB (fp16)
  float* xx      = (float*)(ws + o); o += NROWS * 4;
  float* yy      = (float*)(ws + o); o += DCOLS * 4;
  double* meanacc = (double*)(ws + o); o += 256;
  _Float16* ich  = (_Float16*)(ws + o); o += 3 * DCOLS * 2;      // 48 KiB fp16 rsqrt(colsum-hat)
  float* gtab    = (float*)(ws + o); o += (size_t)NROWS * 8 * 4; // 128 KiB
  float* ploss   = (float*)(ws + o); o += 512 * 4;
  // union region (16 MiB): cs_part (3 MiB, dead after csred) aliased with vpart fp16 (16 MiB)
  float* cs_part = (float*)(ws + o);
  _Float16* vpart = (_Float16*)(ws + o); o += (size_t)8 * NROWS * DIM * 2;           // 16 MiB

  hipMemsetAsync(meanacc, 0, 8, stream);
  k_prep<<<3072, 256, 0, stream>>>(x, ypos, yneg, xb, yb, xx, yy);
  k_transpose<<<dim3(128, 4), 256, 0, stream>>>(ypos, yneg, ybt);
  k_mean<<<dim3(32, 4), 256, 0, stream>>>(xb, yb, xx, yy, meanacc);
  k_diste<<<2048, 512, 0, stream>>>(xb, yb, xx, yy, meanacc, dist, cs_part);
  k_csred<<<96, 256, 0, stream>>>(cs_part, ich);
  k_rowstat<<<4096, 256, 0, stream>>>(dist, ich, gtab);
  k_flash<<<dim3(8, 64), 512, 0, stream>>>(dist, ybt, ich, gtab, vpart);
  k_loss<<<512, 256, 0, stream>>>(vpart, ploss);
  k_finish<<<1, 256, 0, stream>>>(ploss, (float*)d_out);
}